// Round 6
// baseline (552.419 us; speedup 1.0000x reference)
//
#include <hip/hip_runtime.h>
#include <math.h>

#define NUM_NODES 94
#define SEQ_LEN 784
#define OUT_CLASSES 10
#define EPB 32              // 32 batch elements per block = 2 chains x 16
#define NW 6                // 6 waves, tile (16 rows) per wave, tiles 0..5
#define SP 396              // staged-input LDS stride (f32), 2-way max (free)
#define THALF 392           // input staged in two halves
#define YCH 1664            // f16 units per chain's y buffer

#define TWO_GAMMA 0.2f
#define OM2 0.0503551324598949f            // (2*pi/28)^2
#define INV_SQRT_N 0.103142124625879       // 1/sqrt(94)
#define LOG2E 1.4426950408889634
// exp2 arg = 2A*log2e -> fold 2*INV_SQRT_N*LOG2E into W, w_ih, bias (K-slots)
#define WSCALE ((float)(2.0 * INV_SQRT_N * LOG2E))

typedef _Float16 half8 __attribute__((ext_vector_type(8)));
typedef _Float16 half4 __attribute__((ext_vector_type(4)));
typedef _Float16 half2v __attribute__((ext_vector_type(2)));
typedef float    floatx4 __attribute__((ext_vector_type(4)));
typedef float    f2 __attribute__((ext_vector_type(2)));

// R6: DUAL-CHAIN software pipeline. Two independent 16-element recurrences
// (A=elements 0-15, B=16-31) time-multiplexed in the same 6 waves, phase-
// shifted by half a period:
//   [A-compute+publish] [issue B-reads] BAR [B-compute+publish] [issue A-reads] BAR
// Each chain's ds_read latency + MFMA latency + trans latency is covered by
// the OTHER chain's independent compute. Barrier count per chain-step is
// unchanged (1) - this attacks the exposed-latency term that kept R1/R4 at
// ~750 cy/step. Single y buffer per chain (no dbuf): the compiler's
// lgkmcnt(0)+vmcnt(0) drain at __syncthreads guarantees reads complete
// before the cross-phase writes.
// Per-chain math identical to R4 (verified): K=96 with rows 94=s_t, 95=1.0
// folding input+bias into the MFMA; skewed y layout (conflict-free);
// deferred-leak precompute.
__global__
__attribute__((amdgpu_flat_work_group_size(NW*64, NW*64)))
void horn_kernel(
    const float* __restrict__ input,   // (1024, 784)
    const float* __restrict__ w_ih,    // (94, 1)
    const float* __restrict__ b_ih,    // (94)
    const float* __restrict__ w_hh,    // (94, 94)
    const float* __restrict__ b_hh,    // (94)
    const float* __restrict__ w_ro,    // (10, 94)
    const float* __restrict__ b_ro,    // (10)
    float* __restrict__ out)           // (1024, 10)
{
    __shared__ __align__(16) float    sinl[EPB * SP];   // 50,688 B (reused as xsh)
    __shared__ __align__(16) _Float16 ysh[2][YCH];      //  6,656 B (total 57,344)

    const int tid  = threadIdx.x;
    const int w    = tid >> 6;         // wave = tile id 0..5
    const int lane = tid & 63;
    const int e    = lane & 15;        // element-in-chain (B/D col); A row-in-tile
    const int h    = lane >> 4;        // 0..3 (k-group / D row-group)
    const int bb   = blockIdx.x;

    const int  T        = w;
    const bool tailmask = (w == 5 && h == 3);   // rows 92,93 only (94,95 = slots)
    const bool dutyA    = (w == 3 && h == 0);   // refresh s_t slot, chain A
    const bool dutyB    = (w == 2 && h == 0);   // refresh s_t slot, chain B
    const int  sElA     = e;                    // block-element for duty A
    const int  sElB     = 16 + e;               // block-element for duty B

    const int eoff = 104 * e + 4 * (e >> 3);    // skewed base within a chain (f16)

    // ---- zero both chain buffers ----
    for (int i = tid; i < (2 * YCH) / 2; i += NW * 64) ((float*)ysh)[i] = 0.0f;
    __syncthreads();
    // ---- seed rows 94 (s_0) and 95 (1.0) for both chains ----
    if (tid < EPB) {
        const int c  = tid >> 4, ee = tid & 15;
        const int eo = 104 * ee + 4 * (ee >> 3);
        const float s0 = input[((size_t)bb * EPB + tid) * SEQ_LEN];
        half2v v; v[0] = (_Float16)s0; v[1] = (_Float16)1.0f;
        *(half2v*)&ysh[c][eo + NUM_NODES] = v;
    }
    __syncthreads();

    // ---- A fragments (shared by both chains): rows 16T+e; cols 94/95 = w_ih, bias ----
    const int arow = 16 * T + e;
    half8 A0, A1, A2;
    #pragma unroll
    for (int i = 0; i < 8; ++i) {
        const int k = 8 * h + i;
        float v0 = 0.0f, v1 = 0.0f, v2 = 0.0f;
        if (arow < NUM_NODES) {
            v0 = w_hh[arow * NUM_NODES + k] * WSCALE;
            v1 = w_hh[arow * NUM_NODES + k + 32] * WSCALE;
            const int k2 = k + 64;
            if      (k2 <  NUM_NODES) v2 = w_hh[arow * NUM_NODES + k2] * WSCALE;
            else if (k2 == NUM_NODES) v2 = w_ih[arow] * WSCALE;                  // s_t
            else                      v2 = (b_ih[arow] + b_hh[arow]) * WSCALE;   // 1.0
        }
        A0[i] = (_Float16)v0; A1[i] = (_Float16)v1; A2[i] = (_Float16)v2;
    }

    // ---- per-lane state, per chain: rows 16T+4h+{0,1},{2,3} ----
    f2 X0[2], X1[2], Y0[2], Y1[2];
    #pragma unroll
    for (int c = 0; c < 2; ++c) {
        X0[c] = (f2){0,0}; X1[c] = (f2){0,0};
        Y0[c] = (f2){0,0}; Y1[c] = (f2){0,0};
    }

    half4 L0[2], U0[2], L1[2], U1[2], L2[2], U2[2];   // raw B-frag regs per chain

    const f2 no2 = {-OM2, -OM2};
    const f2 p82 = {1.0f - TWO_GAMMA, 1.0f - TWO_GAMMA};
    const f2 h05 = {0.5f, 0.5f};
    const floatx4 zf4 = {0,0,0,0};

    #define READC(C) do {                                                          \
        const _Float16* yb = &ysh[(C)][eoff + 8 * h];                              \
        L0[C] = *(const half4*)(yb);      U0[C] = *(const half4*)(yb + 4);         \
        L1[C] = *(const half4*)(yb + 32); U1[C] = *(const half4*)(yb + 36);        \
        L2[C] = *(const half4*)(yb + 64); U2[C] = *(const half4*)(yb + 68);        \
    } while (0)

    // step t of chain C: consumes L/U[C] (y(t), s_t, 1), publishes y(t+1), s(t+1)
    #define COMPC(C, DUTY, SEL) do {                                               \
        f2 q0 = no2 * X0[C] + h05;  q0 = p82 * Y0[C] + q0;                         \
        f2 q1 = no2 * X1[C] + h05;  q1 = p82 * Y1[C] + q1;                         \
        X0[C] += Y0[C];  X1[C] += Y1[C];                                           \
        float sn = 0.0f;                                                           \
        if (DUTY) {                                                                \
            if (tl + 1 < THALF) sn = sinl[(SEL) * SP + tl + 1];                    \
            else {                                                                 \
                const int tg = (t + 1 < SEQ_LEN) ? t + 1 : (SEQ_LEN - 1);          \
                sn = input[((size_t)bb * EPB + (SEL)) * SEQ_LEN + tg];             \
            }                                                                      \
        }                                                                          \
        half8 B0 = __builtin_shufflevector(L0[C], U0[C], 0,1,2,3,4,5,6,7);         \
        half8 B1 = __builtin_shufflevector(L1[C], U1[C], 0,1,2,3,4,5,6,7);         \
        half8 B2 = __builtin_shufflevector(L2[C], U2[C], 0,1,2,3,4,5,6,7);         \
        floatx4 d  = __builtin_amdgcn_mfma_f32_16x16x32_f16(A0, B0, zf4, 0, 0, 0); \
        floatx4 dp = __builtin_amdgcn_mfma_f32_16x16x32_f16(A1, B1, zf4, 0, 0, 0); \
        d = __builtin_amdgcn_mfma_f32_16x16x32_f16(A2, B2, d, 0, 0, 0);            \
        d += dp;                                                                   \
        f2 r0, r1;                                                                 \
        r0[0] = __builtin_amdgcn_rcpf(__builtin_amdgcn_exp2f(d[0]) + 1.0f);        \
        r0[1] = __builtin_amdgcn_rcpf(__builtin_amdgcn_exp2f(d[1]) + 1.0f);        \
        r1[0] = __builtin_amdgcn_rcpf(__builtin_amdgcn_exp2f(d[2]) + 1.0f);        \
        r1[1] = __builtin_amdgcn_rcpf(__builtin_amdgcn_exp2f(d[3]) + 1.0f);        \
        Y0[C] = q0 - r0;  Y1[C] = q1 - r1;                                         \
        half4 yh;                                                                  \
        yh[0] = (_Float16)Y0[C][0]; yh[1] = (_Float16)Y0[C][1];                    \
        yh[2] = (_Float16)Y1[C][0]; yh[3] = (_Float16)Y1[C][1];                    \
        if (tailmask) {                                                            \
            half2v yt; yt[0] = yh[0]; yt[1] = yh[1];                               \
            *(half2v*)&ysh[C][eoff + 92] = yt;                                     \
        } else {                                                                   \
            *(half4*)&ysh[C][eoff + 16 * T + 4 * h] = yh;                          \
        }                                                                          \
        if (DUTY) {                                                                \
            half2v sv; sv[0] = (_Float16)sn; sv[1] = (_Float16)1.0f;               \
            *(half2v*)&ysh[C][eoff + NUM_NODES] = sv;                              \
        }                                                                          \
    } while (0)

    READC(0);   // prologue: chain-A fragments for step 0

    for (int hf = 0; hf < 2; ++hf) {
        // ---- stage this half of the input (f32, float4-coalesced) ----
        {
            const float* src = input + (size_t)bb * EPB * SEQ_LEN + hf * THALF;
            for (int idx = tid; idx < EPB * (THALF / 4); idx += NW * 64) {
                int ee = idx / (THALF / 4);
                int cc = idx - ee * (THALF / 4);
                *(floatx4*)&sinl[ee * SP + 4 * cc] =
                    *(const floatx4*)(src + (size_t)ee * SEQ_LEN + 4 * cc);
            }
        }
        __syncthreads();   // staging visible (also drains prologue/cross-half reads)

        for (int tl = 0; tl < THALF; ++tl) {
            const int t = hf * THALF + tl;
            COMPC(0, dutyA, sElA);   // step t, chain A (latency covered by prev B)
            READC(1);                // B-frags for step t (covered by BAR + nothing yet)
            __syncthreads();         // BAR1: A-pub visible; B-reads drained
            COMPC(1, dutyB, sElB);   // step t, chain B
            READC(0);                // A-frags for step t+1
            __syncthreads();         // BAR2: B-pub visible; A-reads drained
        }
    }
    #undef COMPC
    #undef READC

    // ---- epilogue: gather x (f32, overlay on sinl), project to classes ----
    float* xsh = sinl;   // loop ended with __syncthreads
    #pragma unroll
    for (int c = 0; c < 2; ++c) {
        floatx4 xv;
        xv[0] = X0[c][0]; xv[1] = X0[c][1]; xv[2] = X1[c][0]; xv[3] = X1[c][1];
        *(floatx4*)&xsh[(16 * c + e) * 100 + 16 * T + 4 * h] = xv;
    }
    __syncthreads();

    if (tid < EPB * OUT_CLASSES) {
        const int ee = tid / OUT_CLASSES;
        const int c  = tid - ee * OUT_CLASSES;
        float acc = b_ro[c];
        #pragma unroll 2
        for (int r = 0; r < NUM_NODES; ++r)
            acc += xsh[ee * 100 + r] * w_ro[c * NUM_NODES + r];
        out[((size_t)bb * EPB + ee) * OUT_CLASSES + c] = acc;
    }
}

extern "C" void kernel_launch(void* const* d_in, const int* in_sizes, int n_in,
                              void* d_out, int out_size, void* d_ws, size_t ws_size,
                              hipStream_t stream) {
    const float* input = (const float*)d_in[0];
    const float* w_ih  = (const float*)d_in[1];
    const float* b_ih  = (const float*)d_in[2];
    const float* w_hh  = (const float*)d_in[3];
    const float* b_hh  = (const float*)d_in[4];
    const float* w_ro  = (const float*)d_in[5];
    const float* b_ro  = (const float*)d_in[6];
    float* out = (float*)d_out;

    const int batch = in_sizes[0] / SEQ_LEN;   // 1024
    dim3 grid(batch / EPB);                    // 32 blocks, 2 chains each
    dim3 block(NW * 64);                       // 6 waves

    hipLaunchKernelGGL(horn_kernel, grid, block, 0, stream,
                       input, w_ih, b_ih, w_hh, b_hh, w_ro, b_ro, out);
}

// Round 7
// 344.625 us; speedup vs baseline: 1.6030x; 1.6030x over previous
//
#include <hip/hip_runtime.h>
#include <math.h>

#define NUM_NODES 94
#define SEQ_LEN 784
#define OUT_CLASSES 10
#define EPB 16              // batch elements per block (MFMA N dim)
#define NW 4                // 4 waves: 1 per SIMD, perfectly balanced
#define SP 788              // staged-input LDS stride (f32): 2-way max (free)
#define YP 104              // y stride per element (f16): b128 slots 13e+h mod 16 bijective

#define TWO_GAMMA 0.2f
#define OM2 0.0503551324598949f            // (2*pi/28)^2
#define INV_SQRT_N 0.103142124625879       // 1/sqrt(94)
#define LOG2E 1.4426950408889634
// exp2 arg = 2A*log2e -> fold 2*INV_SQRT_N*LOG2E into W, w_ih, bias (K-slots)
#define WSCALE ((float)(2.0 * INV_SQRT_N * LOG2E))

typedef _Float16 half8 __attribute__((ext_vector_type(8)));
typedef _Float16 half4 __attribute__((ext_vector_type(4)));
typedef _Float16 half2v __attribute__((ext_vector_type(2)));
typedef float    floatx4 __attribute__((ext_vector_type(4)));
typedef float    f2 __attribute__((ext_vector_type(2)));

// R7: 4 balanced waves (1/SIMD). Wave t owns tile t (rows 16t..16t+15) fully,
// and computes shared tile S=4+(t>>1) REDUNDANTLY with its pair partner
// (redundant MFMA on separate matrix pipes is free), publishing only its
// 8-row half (h<2 for t even, h>=2 for t odd). Eliminates both R4 pathologies:
// no SIMD carries 2 waves, and LDS reads drop 36xb64 -> 12xb128 per step.
// K=96 folding (rows 94=s_t, 95=1.0), deferred-leak precompute, dbuf y.
__global__
__attribute__((amdgpu_flat_work_group_size(NW*64, NW*64)))
void horn_kernel(
    const float* __restrict__ input,   // (1024, 784)
    const float* __restrict__ w_ih,    // (94, 1)
    const float* __restrict__ b_ih,    // (94)
    const float* __restrict__ w_hh,    // (94, 94)
    const float* __restrict__ b_hh,    // (94)
    const float* __restrict__ w_ro,    // (10, 94)
    const float* __restrict__ b_ro,    // (10)
    float* __restrict__ out)           // (1024, 10)
{
    __shared__ __align__(16) float    sinl[EPB * SP];       // 50,432 B (reused as xsh)
    __shared__ __align__(16) _Float16 ybuf[2][EPB * YP];    //  6,656 B (total 57,088)

    const int tid  = threadIdx.x;
    const int w    = tid >> 6;         // wave 0..3 = own tile id
    const int lane = tid & 63;
    const int e    = lane & 15;        // element (B/D col); A row-within-tile
    const int h    = lane >> 4;        // 0..3 (k-group / D row-group)
    const int bb   = blockIdx.x;

    const int  S      = 4 + (w >> 1);            // shared tile (4 or 5)
    const int  sthalf = w & 1;                   // which 8-row half this wave publishes
    const bool shpub  = ((h >> 1) == sthalf);    // lanes that publish shared rows
    const bool duty   = (w == 0 && h == 3);      // refresh s_{t+1} slot (rows 94/95)
    const bool tail53 = (w == 3 && h == 3);      // shared rows 92..95: write only 92,93

    // ---- stage input rows to LDS (16 x 784 f32, float4-coalesced) ----
    {
        const floatx4* in4 = (const floatx4*)(input + (size_t)bb * EPB * SEQ_LEN);
        for (int idx = tid; idx < EPB * (SEQ_LEN / 4); idx += NW * 64) {
            int ee = idx / (SEQ_LEN / 4);
            int cc = idx - ee * (SEQ_LEN / 4);
            *(floatx4*)&sinl[ee * SP + 4 * cc] = in4[idx];
        }
    }
    // ---- zero both y buffers ----
    for (int i = tid; i < (2 * EPB * YP) / 2; i += NW * 64) ((float*)ybuf)[i] = 0.0f;
    __syncthreads();
    // ---- seed buf0 slots: row 94 = s_0, row 95 = 1.0 (buf1 fully written at step 0) ----
    if (tid < EPB) {
        const float s0 = sinl[tid * SP];
        half2v v; v[0] = (_Float16)s0; v[1] = (_Float16)1.0f;
        *(half2v*)&ybuf[0][tid * YP + NUM_NODES] = v;
    }
    __syncthreads();

    // ---- A fragments, own tile + shared tile; K-cols 94/95 carry w_ih / bias ----
    #define LOAD_A(ROW, A0, A1, A2) do {                                           \
        const int arow = (ROW);                                                    \
        _Pragma("unroll")                                                          \
        for (int i = 0; i < 8; ++i) {                                              \
            const int k = 8 * h + i;                                               \
            float v0 = 0.0f, v1 = 0.0f, v2 = 0.0f;                                 \
            if (arow < NUM_NODES) {                                                \
                v0 = w_hh[arow * NUM_NODES + k] * WSCALE;                          \
                v1 = w_hh[arow * NUM_NODES + k + 32] * WSCALE;                     \
                const int k2 = k + 64;                                             \
                if      (k2 <  NUM_NODES) v2 = w_hh[arow * NUM_NODES + k2] * WSCALE; \
                else if (k2 == NUM_NODES) v2 = w_ih[arow] * WSCALE;                \
                else                      v2 = (b_ih[arow] + b_hh[arow]) * WSCALE; \
            }                                                                      \
            (A0)[i] = (_Float16)v0; (A1)[i] = (_Float16)v1; (A2)[i] = (_Float16)v2;\
        }                                                                          \
    } while (0)

    half8 AO0, AO1, AO2, AS0, AS1, AS2;
    LOAD_A(16 * w + e, AO0, AO1, AO2);
    LOAD_A(16 * S + e, AS0, AS1, AS2);
    #undef LOAD_A

    // ---- per-lane state: own rows 16w+4h+{0..3}; shared rows 16S+4h+{0..3} ----
    f2 xo01 = {0,0}, xo23 = {0,0}, yo01 = {0,0}, yo23 = {0,0};
    f2 xs01 = {0,0}, xs23 = {0,0}, ys01 = {0,0}, ys23 = {0,0};

    const f2 no2 = {-OM2, -OM2};
    const f2 p82 = {1.0f - TWO_GAMMA, 1.0f - TWO_GAMMA};
    const f2 h05 = {0.5f, 0.5f};
    const floatx4 zf4 = {0,0,0,0};

    #define HSTEP(RP, WP, T_) do {                                                 \
        const _Float16* yb = &ybuf[RP][e * YP + 8 * h];                            \
        half8 B0 = *(const half8*)(yb);                                            \
        half8 B1 = *(const half8*)(yb + 32);                                       \
        half8 B2 = *(const half8*)(yb + 64);                                       \
        float sn = 0.0f;                                                           \
        if (duty) {                                                                \
            const int tn = ((T_) + 1 < SEQ_LEN) ? (T_) + 1 : (SEQ_LEN - 1);        \
            sn = sinl[e * SP + tn];                                                \
        }                                                                          \
        /* deferred-leak precompute fills the read/MFMA latency */                 \
        f2 qo0 = no2 * xo01 + h05;  qo0 = p82 * yo01 + qo0;                        \
        f2 qo1 = no2 * xo23 + h05;  qo1 = p82 * yo23 + qo1;                        \
        f2 qs0 = no2 * xs01 + h05;  qs0 = p82 * ys01 + qs0;                        \
        f2 qs1 = no2 * xs23 + h05;  qs1 = p82 * ys23 + qs1;                        \
        xo01 += yo01;  xo23 += yo23;  xs01 += ys01;  xs23 += ys23;                 \
        /* own tile: 2-parallel MFMA chains, depth 2 */                            \
        floatx4 dO  = __builtin_amdgcn_mfma_f32_16x16x32_f16(AO0, B0, zf4, 0, 0, 0); \
        floatx4 dOp = __builtin_amdgcn_mfma_f32_16x16x32_f16(AO1, B1, zf4, 0, 0, 0); \
        floatx4 dS  = __builtin_amdgcn_mfma_f32_16x16x32_f16(AS0, B0, zf4, 0, 0, 0); \
        floatx4 dSp = __builtin_amdgcn_mfma_f32_16x16x32_f16(AS1, B1, zf4, 0, 0, 0); \
        dO = __builtin_amdgcn_mfma_f32_16x16x32_f16(AO2, B2, dO, 0, 0, 0);         \
        dS = __builtin_amdgcn_mfma_f32_16x16x32_f16(AS2, B2, dS, 0, 0, 0);         \
        dO += dOp;  dS += dSp;   /* = full exp2 arguments */                       \
        f2 r0, r1;                                                                 \
        r0[0] = __builtin_amdgcn_rcpf(__builtin_amdgcn_exp2f(dO[0]) + 1.0f);       \
        r0[1] = __builtin_amdgcn_rcpf(__builtin_amdgcn_exp2f(dO[1]) + 1.0f);       \
        r1[0] = __builtin_amdgcn_rcpf(__builtin_amdgcn_exp2f(dO[2]) + 1.0f);       \
        r1[1] = __builtin_amdgcn_rcpf(__builtin_amdgcn_exp2f(dO[3]) + 1.0f);       \
        yo01 = qo0 - r0;  yo23 = qo1 - r1;                                         \
        half4 yh;                                                                  \
        yh[0] = (_Float16)yo01[0]; yh[1] = (_Float16)yo01[1];                      \
        yh[2] = (_Float16)yo23[0]; yh[3] = (_Float16)yo23[1];                      \
        *(half4*)&ybuf[WP][e * YP + 16 * w + 4 * h] = yh;  /* own rows < 64 */     \
        f2 s0_, s1_;                                                               \
        s0_[0] = __builtin_amdgcn_rcpf(__builtin_amdgcn_exp2f(dS[0]) + 1.0f);      \
        s0_[1] = __builtin_amdgcn_rcpf(__builtin_amdgcn_exp2f(dS[1]) + 1.0f);      \
        s1_[0] = __builtin_amdgcn_rcpf(__builtin_amdgcn_exp2f(dS[2]) + 1.0f);      \
        s1_[1] = __builtin_amdgcn_rcpf(__builtin_amdgcn_exp2f(dS[3]) + 1.0f);      \
        ys01 = qs0 - s0_;  ys23 = qs1 - s1_;                                       \
        half4 yhs;                                                                 \
        yhs[0] = (_Float16)ys01[0]; yhs[1] = (_Float16)ys01[1];                    \
        yhs[2] = (_Float16)ys23[0]; yhs[3] = (_Float16)ys23[1];                    \
        if (shpub) {                                                               \
            if (tail53) {                                                          \
                half2v yt; yt[0] = yhs[0]; yt[1] = yhs[1];  /* rows 92,93 */       \
                *(half2v*)&ybuf[WP][e * YP + 92] = yt;                             \
            } else {                                                               \
                *(half4*)&ybuf[WP][e * YP + 16 * S + 4 * h] = yhs;                 \
            }                                                                      \
        }                                                                          \
        if (duty) {                                                                \
            half2v sv; sv[0] = (_Float16)sn; sv[1] = (_Float16)1.0f;               \
            *(half2v*)&ybuf[WP][e * YP + NUM_NODES] = sv;                          \
        }                                                                          \
        __syncthreads();                                                           \
    } while (0)

    for (int t = 0; t < SEQ_LEN; t += 2) {
        HSTEP(0, 1, t);
        HSTEP(1, 0, t + 1);
    }
    #undef HSTEP

    // ---- epilogue: gather x (f32, overlay on sinl), project to classes ----
    float* xsh = sinl;   // last HSTEP ended with __syncthreads
    {
        floatx4 xv;
        xv[0] = xo01[0]; xv[1] = xo01[1]; xv[2] = xo23[0]; xv[3] = xo23[1];
        *(floatx4*)&xsh[e * 100 + 16 * w + 4 * h] = xv;
        if (shpub) {
            floatx4 xw;
            xw[0] = xs01[0]; xw[1] = xs01[1]; xw[2] = xs23[0]; xw[3] = xs23[1];
            *(floatx4*)&xsh[e * 100 + 16 * S + 4 * h] = xw;   // rows 94,95 unread
        }
    }
    __syncthreads();

    if (tid < EPB * OUT_CLASSES) {
        const int ee = tid / OUT_CLASSES;
        const int c  = tid - ee * OUT_CLASSES;
        float acc = b_ro[c];
        #pragma unroll 2
        for (int r = 0; r < NUM_NODES; ++r)
            acc += xsh[ee * 100 + r] * w_ro[c * NUM_NODES + r];
        out[((size_t)bb * EPB + ee) * OUT_CLASSES + c] = acc;
    }
}

extern "C" void kernel_launch(void* const* d_in, const int* in_sizes, int n_in,
                              void* d_out, int out_size, void* d_ws, size_t ws_size,
                              hipStream_t stream) {
    const float* input = (const float*)d_in[0];
    const float* w_ih  = (const float*)d_in[1];
    const float* b_ih  = (const float*)d_in[2];
    const float* w_hh  = (const float*)d_in[3];
    const float* b_hh  = (const float*)d_in[4];
    const float* w_ro  = (const float*)d_in[5];
    const float* b_ro  = (const float*)d_in[6];
    float* out = (float*)d_out;

    const int batch = in_sizes[0] / SEQ_LEN;   // 1024
    dim3 grid(batch / EPB);                    // 64 blocks of 16 elements
    dim3 block(NW * 64);                       // 4 waves, 1 per SIMD

    hipLaunchKernelGGL(horn_kernel, grid, block, 0, stream,
                       input, w_ih, b_ih, w_hh, b_hh, w_ro, b_ro, out);
}

// Round 8
// 298.311 us; speedup vs baseline: 1.8518x; 1.1553x over previous
//
#include <hip/hip_runtime.h>
#include <math.h>

#define NUM_NODES 94
#define SEQ_LEN 784
#define OUT_CLASSES 10
#define EPB 16              // batch elements per block (MFMA N dim)
#define NW 8                // 8 waves: every SIMD gets 1 full + 1 half wave
#define SP 788              // staged-input LDS stride (f32): 2-way max (free)
#define YP 104              // y stride per element (f16), R4-verified skewed layout

#define TWO_GAMMA 0.2f
#define OM2 0.0503551324598949f            // (2*pi/28)^2
#define INV_SQRT_N 0.103142124625879       // 1/sqrt(94)
#define LOG2E 1.4426950408889634
// exp2 arg = 2A*log2e -> fold 2*INV_SQRT_N*LOG2E into W, w_ih, bias (K-slots)
#define WSCALE ((float)(2.0 * INV_SQRT_N * LOG2E))

typedef _Float16 half8 __attribute__((ext_vector_type(8)));
typedef _Float16 half4 __attribute__((ext_vector_type(4)));
typedef _Float16 half2v __attribute__((ext_vector_type(2)));
typedef float    floatx4 __attribute__((ext_vector_type(4)));
typedef float    f2 __attribute__((ext_vector_type(2)));

// R8: trans-port-balanced 8-wave split. v_exp/v_rcp are quarter-rate (16
// issue-cy per wave64 op); the 47 wave-trans per block-step are the dominant
// per-SIMD port cost. Waves 0-3: full tiles 0-3 (8 trans/lane). Waves 4-7:
// tiles 4,5 in redundant pairs (MFMA recomputed - matrix pipe is idle), each
// wave runs dynamics/publish for 2 of the 4 D-rows (4 trans/lane). Every
// SIMD: 1 full + 1 half wave = 192 trans-cy, uniform -> minimal barrier
// laggard, and 2 waves/SIMD overlap each other's latencies.
// Reads: R4's verified skewed b64 pattern (54K conflicts). K=96 folding:
// rows 94=s_t, 95=1.0; duty = wave 7 h=3 (its D-rows ARE 94/95 - no loss).
// y layout: element e base = 104e + 4*(e>>3) f16 units.
__global__
__attribute__((amdgpu_flat_work_group_size(NW*64, NW*64)))
void horn_kernel(
    const float* __restrict__ input,   // (1024, 784)
    const float* __restrict__ w_ih,    // (94, 1)
    const float* __restrict__ b_ih,    // (94)
    const float* __restrict__ w_hh,    // (94, 94)
    const float* __restrict__ b_hh,    // (94)
    const float* __restrict__ w_ro,    // (10, 94)
    const float* __restrict__ b_ro,    // (10)
    float* __restrict__ out)           // (1024, 10)
{
    __shared__ __align__(16) float    sinl[EPB * SP];       // 50,432 B (reused as xsh)
    __shared__ __align__(16) _Float16 ybuf[2][EPB * YP];    //  6,656 B (total 57,088)

    const int tid  = threadIdx.x;
    const int w    = tid >> 6;         // wave 0..7
    const int lane = tid & 63;
    const int e    = lane & 15;        // element (B/D col); A row-within-tile
    const int h    = lane >> 4;        // 0..3 (k-group / D row-group)
    const int bb   = blockIdx.x;

    const bool isfull = (w < 4);
    const int  T      = isfull ? w : (4 + ((w - 4) >> 1));   // owned tile
    const int  p      = (w - 4) & 1;   // half-wave parity: D rows 4h+2p,4h+2p+1
    const bool duty   = (w == 7) && (h == 3);   // D rows 94,95 = input slots

    const int eoff = 104 * e + 4 * (e >> 3);    // skewed element base (f16 units)

    // ---- stage input rows to LDS (16 x 784 f32, float4-coalesced) ----
    {
        const floatx4* in4 = (const floatx4*)(input + (size_t)bb * EPB * SEQ_LEN);
        for (int idx = tid; idx < EPB * (SEQ_LEN / 4); idx += NW * 64) {
            int ee = idx / (SEQ_LEN / 4);
            int cc = idx - ee * (SEQ_LEN / 4);
            *(floatx4*)&sinl[ee * SP + 4 * cc] = in4[idx];
        }
    }
    // ---- zero both y buffers ----
    for (int i = tid; i < (2 * EPB * YP) / 2; i += NW * 64) ((float*)ybuf)[i] = 0.0f;
    __syncthreads();
    // ---- seed buf0: row 94 = s_0, row 95 = 1.0 (SKEWED offset - R4 bug fix) ----
    if (tid < EPB) {
        const int eo = 104 * tid + 4 * (tid >> 3);
        const float s0 = sinl[tid * SP];
        half2v v; v[0] = (_Float16)s0; v[1] = (_Float16)1.0f;
        *(half2v*)&ybuf[0][eo + NUM_NODES] = v;
    }
    __syncthreads();

    // ---- A fragments for tile T; K-cols 94/95 carry w_ih / bias ----
    const int arow = 16 * T + e;
    half8 A0, A1, A2;
    #pragma unroll
    for (int i = 0; i < 8; ++i) {
        const int k = 8 * h + i;
        float v0 = 0.0f, v1 = 0.0f, v2 = 0.0f;
        if (arow < NUM_NODES) {
            v0 = w_hh[arow * NUM_NODES + k] * WSCALE;
            v1 = w_hh[arow * NUM_NODES + k + 32] * WSCALE;
            const int k2 = k + 64;
            if      (k2 <  NUM_NODES) v2 = w_hh[arow * NUM_NODES + k2] * WSCALE;
            else if (k2 == NUM_NODES) v2 = w_ih[arow] * WSCALE;                  // s_t
            else                      v2 = (b_ih[arow] + b_hh[arow]) * WSCALE;   // 1.0
        }
        A0[i] = (_Float16)v0; A1[i] = (_Float16)v1; A2[i] = (_Float16)v2;
    }

    // ---- per-lane state: full waves 4 nodes (x01/x23); half waves 2 (x01) ----
    f2 x01 = {0,0}, x23 = {0,0}, y01 = {0,0}, y23 = {0,0};

    const f2 no2 = {-OM2, -OM2};
    const f2 p82 = {1.0f - TWO_GAMMA, 1.0f - TWO_GAMMA};   // 0.8
    const f2 h05 = {0.5f, 0.5f};
    const floatx4 zf4 = {0,0,0,0};

    #define HSTEP(RP, WP, T_) do {                                                 \
        const _Float16* yb = &ybuf[RP][eoff + 8 * h];                              \
        half4 l0 = *(const half4*)(yb);                                            \
        half4 u0 = *(const half4*)(yb + 4);                                        \
        half4 l1 = *(const half4*)(yb + 32);                                       \
        half4 u1 = *(const half4*)(yb + 36);                                       \
        half4 l2 = *(const half4*)(yb + 64);                                       \
        half4 u2 = *(const half4*)(yb + 68);                                       \
        float sn = 0.0f;                                                           \
        if (duty) {                                                                \
            const int tn = ((T_) + 1 < SEQ_LEN) ? (T_) + 1 : (SEQ_LEN - 1);        \
            sn = sinl[e * SP + tn];                                                \
        }                                                                          \
        /* deferred-leak precompute fills the read/MFMA latency */                 \
        f2 q0 = no2 * x01 + h05;  q0 = p82 * y01 + q0;                             \
        x01 += y01;                                                                \
        f2 q1 = {0.0f, 0.0f};                                                      \
        if (isfull) {                                                              \
            q1 = no2 * x23 + h05;  q1 = p82 * y23 + q1;                            \
            x23 += y23;                                                            \
        }                                                                          \
        half8 B0 = __builtin_shufflevector(l0, u0, 0, 1, 2, 3, 4, 5, 6, 7);        \
        half8 B1 = __builtin_shufflevector(l1, u1, 0, 1, 2, 3, 4, 5, 6, 7);        \
        half8 B2 = __builtin_shufflevector(l2, u2, 0, 1, 2, 3, 4, 5, 6, 7);        \
        floatx4 d0 = __builtin_amdgcn_mfma_f32_16x16x32_f16(A0, B0, zf4, 0, 0, 0); \
        floatx4 d1 = __builtin_amdgcn_mfma_f32_16x16x32_f16(A1, B1, zf4, 0, 0, 0); \
        floatx4 d2 = __builtin_amdgcn_mfma_f32_16x16x32_f16(A2, B2, zf4, 0, 0, 0); \
        floatx4 d = (d0 + d1) + d2;   /* full exp2 argument (bias+input in K) */   \
        if (isfull) {                                                              \
            f2 r0, r1;                                                             \
            r0[0] = __builtin_amdgcn_rcpf(__builtin_amdgcn_exp2f(d[0]) + 1.0f);    \
            r0[1] = __builtin_amdgcn_rcpf(__builtin_amdgcn_exp2f(d[1]) + 1.0f);    \
            r1[0] = __builtin_amdgcn_rcpf(__builtin_amdgcn_exp2f(d[2]) + 1.0f);    \
            r1[1] = __builtin_amdgcn_rcpf(__builtin_amdgcn_exp2f(d[3]) + 1.0f);    \
            y01 = q0 - r0;  y23 = q1 - r1;                                         \
            half4 yh;                                                              \
            yh[0] = (_Float16)y01[0]; yh[1] = (_Float16)y01[1];                    \
            yh[2] = (_Float16)y23[0]; yh[3] = (_Float16)y23[1];                    \
            *(half4*)&ybuf[WP][eoff + 16 * T + 4 * h] = yh;                        \
        } else {                                                                   \
            f2 dv;                                                                 \
            if (p == 0) { dv[0] = d[0]; dv[1] = d[1]; }                            \
            else        { dv[0] = d[2]; dv[1] = d[3]; }                            \
            f2 r;                                                                  \
            r[0] = __builtin_amdgcn_rcpf(__builtin_amdgcn_exp2f(dv[0]) + 1.0f);    \
            r[1] = __builtin_amdgcn_rcpf(__builtin_amdgcn_exp2f(dv[1]) + 1.0f);    \
            y01 = q0 - r;                                                          \
            if (duty) {                                                            \
                half2v sv; sv[0] = (_Float16)sn; sv[1] = (_Float16)1.0f;           \
                *(half2v*)&ybuf[WP][eoff + NUM_NODES] = sv;                        \
            } else {                                                               \
                half2v yh2; yh2[0] = (_Float16)y01[0]; yh2[1] = (_Float16)y01[1];  \
                *(half2v*)&ybuf[WP][eoff + 16 * T + 4 * h + 2 * p] = yh2;          \
            }                                                                      \
        }                                                                          \
        __syncthreads();                                                           \
    } while (0)

    for (int t = 0; t < SEQ_LEN; t += 2) {
        HSTEP(0, 1, t);
        HSTEP(1, 0, t + 1);
    }
    #undef HSTEP

    // ---- epilogue: gather x (f32, overlay on sinl), project to classes ----
    float* xsh = sinl;   // last HSTEP ended with __syncthreads
    if (isfull) {
        floatx4 xv;
        xv[0] = x01[0]; xv[1] = x01[1]; xv[2] = x23[0]; xv[3] = x23[1];
        *(floatx4*)&xsh[e * 100 + 16 * T + 4 * h] = xv;
    } else {
        f2 xv; xv[0] = x01[0]; xv[1] = x01[1];
        *(f2*)&xsh[e * 100 + 16 * T + 4 * h + 2 * p] = xv;   // rows 94,95 unread
    }
    __syncthreads();

    if (tid < EPB * OUT_CLASSES) {
        const int ee = tid / OUT_CLASSES;
        const int c  = tid - ee * OUT_CLASSES;
        float acc = b_ro[c];
        #pragma unroll 2
        for (int r = 0; r < NUM_NODES; ++r)
            acc += xsh[ee * 100 + r] * w_ro[c * NUM_NODES + r];
        out[((size_t)bb * EPB + ee) * OUT_CLASSES + c] = acc;
    }
}

extern "C" void kernel_launch(void* const* d_in, const int* in_sizes, int n_in,
                              void* d_out, int out_size, void* d_ws, size_t ws_size,
                              hipStream_t stream) {
    const float* input = (const float*)d_in[0];
    const float* w_ih  = (const float*)d_in[1];
    const float* b_ih  = (const float*)d_in[2];
    const float* w_hh  = (const float*)d_in[3];
    const float* b_hh  = (const float*)d_in[4];
    const float* w_ro  = (const float*)d_in[5];
    const float* b_ro  = (const float*)d_in[6];
    float* out = (float*)d_out;

    const int batch = in_sizes[0] / SEQ_LEN;   // 1024
    dim3 grid(batch / EPB);                    // 64 blocks of 16 elements
    dim3 block(NW * 64);                       // 8 waves: 1 full + 1 half per SIMD

    hipLaunchKernelGGL(horn_kernel, grid, block, 0, stream,
                       input, w_ih, b_ih, w_hh, b_hh, w_ro, b_ro, out);
}